// Round 6
// baseline (360.891 us; speedup 1.0000x reference)
//
#include <hip/hip_runtime.h>
#include <hip/hip_bf16.h>

// ============================================================================
// MEASUREMENT ROUND: exact round-1 (282 us) structure, with aggregate_bn and
// mm_f16_relu internally AMPLIFIED 2x (double work, halved result -- output
// identical) so they exceed the harness's 44us fill dispatches and surface in
// the rocprof top-5 with full counters. 3A+3M = total - 282.
// ============================================================================

constexpr int N = 10000;   // nodes
constexpr int D = 512;     // feature dim
constexpr int E = 160000;  // edges
constexpr int L = 3;       // layers
constexpr float EPS = 1e-5f;

typedef _Float16 half8 __attribute__((ext_vector_type(8)));
typedef _Float16 half2v __attribute__((ext_vector_type(2)));
typedef float floatx4 __attribute__((ext_vector_type(4)));

// async global->LDS, 16B per lane. LDS dest = wave-uniform base + lane*16.
__device__ __forceinline__ void glds16(const _Float16* g, _Float16* l) {
    __builtin_amdgcn_global_load_lds(
        (const __attribute__((address_space(1))) uint32_t*)(g),
        (__attribute__((address_space(3))) uint32_t*)(l),
        16, 0, 0);
}

// ---------------------------------------------------------------------------
// Mega setup: degrees + x fp32->f16 conversion + column stats + W transpose.
// Roles by blockIdx.x.
// ---------------------------------------------------------------------------
constexpr int DEG_BLOCKS  = (E + 255) / 256;   // 625
constexpr int CONV_BLOCKS = 100;               // 100 rows each
constexpr int TW_BLOCKS   = L * 256;           // 768 (32x32 tiles)
constexpr int MEGA_BLOCKS = DEG_BLOCKS + CONV_BLOCKS + TW_BLOCKS;

__global__ __launch_bounds__(256) void mega_setup(
    const int* __restrict__ src, const int* __restrict__ dst,
    const float* __restrict__ x, const float* __restrict__ W,
    int* __restrict__ out_deg, int* __restrict__ in_deg,
    _Float16* __restrict__ x16, float* __restrict__ stats0,
    _Float16* __restrict__ Wt) {
    __shared__ float tb[32][33];
    int bid = blockIdx.x;
    int tid = threadIdx.x;
    if (bid < DEG_BLOCKS) {
        int e = bid * 256 + tid;
        if (e < E) {
            atomicAdd(&out_deg[src[e]], 1);
            atomicAdd(&in_deg[dst[e]], 1);
        }
    } else if (bid < DEG_BLOCKS + CONV_BLOCKS) {
        int b = bid - DEG_BLOCKS;
        int r0 = b * 100;
        int r1 = r0 + 100; if (r1 > N) r1 = N;
        int c2 = tid * 2;
        float s0 = 0.f, s1 = 0.f, q0 = 0.f, q1 = 0.f;
        for (int r = r0; r < r1; ++r) {
            float2 v = *(const float2*)(x + (size_t)r * D + c2);
            s0 += v.x; q0 += v.x * v.x;
            s1 += v.y; q1 += v.y * v.y;
            half2v h; h[0] = (_Float16)v.x; h[1] = (_Float16)v.y;
            *(half2v*)(x16 + (size_t)r * D + c2) = h;
        }
        atomicAdd(&stats0[c2], s0);
        atomicAdd(&stats0[c2 + 1], s1);
        atomicAdd(&stats0[D + c2], q0);
        atomicAdd(&stats0[D + c2 + 1], q1);
    } else {
        int b = bid - DEG_BLOCKS - CONV_BLOCKS;  // 0..767
        int l = b >> 8;
        int t = b & 255;
        int k0 = (t >> 4) * 32, n0 = (t & 15) * 32;
        int tx = tid & 31, ty = tid >> 5;  // 32 x 8
        const float* Wl = W + (size_t)l * D * D;
        _Float16* Wtl = Wt + (size_t)l * D * D;
        for (int i = 0; i < 32; i += 8)
            tb[ty + i][tx] = Wl[(size_t)(k0 + ty + i) * D + n0 + tx];
        __syncthreads();
        for (int i = 0; i < 32; i += 8)
            Wtl[(size_t)(n0 + ty + i) * D + k0 + tx] = (_Float16)tb[tx][ty + i];
    }
}

// ---------------------------------------------------------------------------
// Single block: exclusive scan of in_deg -> off & cursor, plus both norms.
// ---------------------------------------------------------------------------
__global__ void scan_indeg(const int* __restrict__ in_deg,
                           const int* __restrict__ out_deg,
                           int* __restrict__ off, int* __restrict__ cursor,
                           float* __restrict__ src_norm, float* __restrict__ dst_norm) {
    __shared__ int lsum[1024];
    int t = threadIdx.x;
    const int chunk = (N + 1023) / 1024;
    int start = t * chunk;
    int end = start + chunk; if (end > N) end = N;
    int s = 0;
    for (int i = start; i < end; ++i) s += in_deg[i];
    lsum[t] = s;
    __syncthreads();
    for (int d = 1; d < 1024; d <<= 1) {
        int v = (t >= d) ? lsum[t - d] : 0;
        __syncthreads();
        lsum[t] += v;
        __syncthreads();
    }
    int excl = (t == 0) ? 0 : lsum[t - 1];
    for (int i = start; i < end; ++i) {
        off[i] = excl;
        cursor[i] = excl;
        excl += in_deg[i];
        int od = out_deg[i]; if (od < 1) od = 1;
        int id = in_deg[i];  if (id < 1) id = 1;
        src_norm[i] = rsqrtf((float)od);
        dst_norm[i] = rsqrtf((float)id);
    }
    if (t == 1023) off[N] = lsum[1023];
}

__global__ void csr_fill(const int* __restrict__ src, const int* __restrict__ dst,
                         int* __restrict__ cursor, int* __restrict__ csr_src) {
    int e = blockIdx.x * blockDim.x + threadIdx.x;
    if (e >= E) return;
    int d = dst[e];
    int pos = atomicAdd(&cursor[d], 1);
    csr_src[pos] = src[e];
}

// ---------------------------------------------------------------------------
// Fused BN + gather-aggregate, coef in-register from stats. One wave per node.
// 4x edge unroll: 4 independent 1KB row loads in flight per iteration.
// AMPLIFIED 2x: edge loop runs twice, result halved (output identical).
// ---------------------------------------------------------------------------
__global__ __launch_bounds__(256) void aggregate_bn(
    const _Float16* __restrict__ x, const int* __restrict__ off,
    const int* __restrict__ csr_src, const float* __restrict__ src_norm,
    const float* __restrict__ dst_norm, const float* __restrict__ stats,
    const float* __restrict__ gamma, const float* __restrict__ beta,
    _Float16* __restrict__ agg) {
    int wid = (blockIdx.x * 256 + threadIdx.x) >> 6;
    if (wid >= N) return;
    int lane = threadIdx.x & 63;
    int c0 = lane * 8;

    float scale[8], shift[8];
    const float invN = 1.0f / (float)N;
    for (int i = 0; i < 8; ++i) {
        int c = c0 + i;
        float mu = stats[c] * invN;
        float var = stats[D + c] * invN - mu * mu;
        float sc = gamma[c] * rsqrtf(var + EPS);
        scale[i] = sc;
        shift[i] = beta[c] - mu * sc;
    }

    int e0 = off[wid], e1 = off[wid + 1];
    float a[8] = {}, a2[8] = {};
    float t = 0.f;
    for (int rep = 0; rep < 2; ++rep) {
        int e = e0;
        for (; e + 4 <= e1; e += 4) {
            int s0 = csr_src[e];
            int s1 = csr_src[e + 1];
            int s2 = csr_src[e + 2];
            int s3 = csr_src[e + 3];
            float n0 = src_norm[s0];
            float n1 = src_norm[s1];
            float n2 = src_norm[s2];
            float n3 = src_norm[s3];
            half8 v0 = *(const half8*)(x + (size_t)s0 * D + c0);
            half8 v1 = *(const half8*)(x + (size_t)s1 * D + c0);
            half8 v2 = *(const half8*)(x + (size_t)s2 * D + c0);
            half8 v3 = *(const half8*)(x + (size_t)s3 * D + c0);
            t += (n0 + n1) + (n2 + n3);
            for (int k = 0; k < 8; ++k) {
                a[k]  += (float)v0[k] * n0;
                a2[k] += (float)v1[k] * n1;
                a[k]  += (float)v2[k] * n2;
                a2[k] += (float)v3[k] * n3;
            }
        }
        for (; e < e1; ++e) {
            int s0 = csr_src[e];
            float n0 = src_norm[s0];
            half8 v0 = *(const half8*)(x + (size_t)s0 * D + c0);
            t += n0;
            for (int k = 0; k < 8; ++k) a[k] += (float)v0[k] * n0;
        }
    }
    float dn = dst_norm[wid];
    half8 o;
    for (int i = 0; i < 8; ++i)
        o[i] = (_Float16)(dn * (scale[i] * (0.5f * (a[i] + a2[i])) +
                                shift[i] * (0.5f * t)));
    *(half8*)(agg + (size_t)wid * D + c0) = o;
}

// ---------------------------------------------------------------------------
// C = relu(A @ W + bias) via f16 MFMA with global_load_lds staging.
// A: M x 512 f16.  Bt[n][k] = W[k][n] f16.
// Block 256 = 4 waves; tile 128(M) x 128(N); BK=32.
// Wave computes 64x64 (4x4 tiles of mfma_f32_16x16x32_f16).
// AMPLIFIED 2x: K-loop runs twice (acc = 2*AW), epilogue halves (identical).
// ---------------------------------------------------------------------------
template <typename OutT, bool STATS>
__global__ __launch_bounds__(256) void mm_f16_relu(
    const _Float16* __restrict__ A, const _Float16* __restrict__ Bt,
    const float* __restrict__ bias, OutT* __restrict__ C, int M,
    float* __restrict__ stats) {
    __shared__ __align__(16) _Float16 As[128 * 32];
    __shared__ __align__(16) _Float16 Bs[128 * 32];
    const int tid  = threadIdx.x;
    const int wave = tid >> 6;
    const int lane = tid & 63;
    const int quad = lane >> 4;
    const int l16  = lane & 15;
    const int row0 = blockIdx.x * 128;
    const int col0 = blockIdx.y * 128;
    const int wm = (wave & 1) * 64;
    const int wn = (wave >> 1) * 64;
    const int sr = lane >> 2;
    const int sc = (lane & 3) * 8;

    int ar0 = row0 + wave * 32 + sr;
    int ar1 = ar0 + 16;
    if (ar0 >= M) ar0 = M - 1;
    if (ar1 >= M) ar1 = M - 1;
    const _Float16* gA0 = A + (size_t)ar0 * D + sc;
    const _Float16* gA1 = A + (size_t)ar1 * D + sc;
    const _Float16* gB0 = Bt + (size_t)(col0 + wave * 32 + sr) * D + sc;
    const _Float16* gB1 = Bt + (size_t)(col0 + wave * 32 + 16 + sr) * D + sc;
    _Float16* lA0 = As + (wave * 32) * 32;
    _Float16* lA1 = As + (wave * 32 + 16) * 32;
    _Float16* lB0 = Bs + (wave * 32) * 32;
    _Float16* lB1 = Bs + (wave * 32 + 16) * 32;

    floatx4 acc[4][4] = {};

    for (int rep = 0; rep < 2; ++rep) {
        for (int k0 = 0; k0 < D; k0 += 32) {
            __syncthreads();
            glds16(gA0 + k0, lA0);
            glds16(gA1 + k0, lA1);
            glds16(gB0 + k0, lB0);
            glds16(gB1 + k0, lB1);
            __syncthreads();  // compiler inserts vmcnt(0) drain here
            half8 af[4], bf[4];
            for (int i = 0; i < 4; ++i)
                af[i] = *(const half8*)(As + (wm + i * 16 + l16) * 32 + quad * 8);
            for (int j = 0; j < 4; ++j)
                bf[j] = *(const half8*)(Bs + (wn + j * 16 + l16) * 32 + quad * 8);
            for (int i = 0; i < 4; ++i)
                for (int j = 0; j < 4; ++j)
                    acc[i][j] = __builtin_amdgcn_mfma_f32_16x16x32_f16(
                        af[i], bf[j], acc[i][j], 0, 0, 0);
        }
    }

    // epilogue: C/D layout col = lane&15, row = quad*4 + reg
    float s[4] = {}, q[4] = {};
    for (int i = 0; i < 4; ++i) {
        for (int r = 0; r < 4; ++r) {
            int row = row0 + wm + i * 16 + quad * 4 + r;
            bool valid = row < M;
            for (int j = 0; j < 4; ++j) {
                int col = col0 + wn + j * 16 + l16;
                float v = 0.5f * acc[i][j][r] + bias[col];
                v = v > 0.f ? v : 0.f;
                if (valid) {
                    C[(size_t)row * D + col] = (OutT)v;
                    if (STATS) { s[j] += v; q[j] += v * v; }
                }
            }
        }
    }
    if (STATS) {
        for (int j = 0; j < 4; ++j) {
            float sv = s[j], qv = q[j];
            sv += __shfl_xor(sv, 16); sv += __shfl_xor(sv, 32);
            qv += __shfl_xor(qv, 16); qv += __shfl_xor(qv, 32);
            if (quad == 0) {
                int col = col0 + wn + j * 16 + l16;
                atomicAdd(&stats[col], sv);
                atomicAdd(&stats[D + col], qv);
            }
        }
    }
}

// ---------------------------------------------------------------------------
extern "C" void kernel_launch(void* const* d_in, const int* in_sizes, int n_in,
                              void* d_out, int out_size, void* d_ws, size_t ws_size,
                              hipStream_t stream) {
    const float* x_in  = (const float*)d_in[0];
    const int*   src   = (const int*)d_in[1];
    const int*   dst   = (const int*)d_in[2];
    const float* gamma = (const float*)d_in[3];
    const float* beta  = (const float*)d_in[4];
    const float* W     = (const float*)d_in[5];
    const float* b     = (const float*)d_in[6];
    float* out = (float*)d_out;

    // workspace carve-up (16B-aligned segments first)
    char* p = (char*)d_ws;
    _Float16* x16 = (_Float16*)p;  p += (size_t)N * D * 2;       // 10.24 MB
    _Float16* agg = (_Float16*)p;  p += (size_t)N * D * 2;       // 10.24 MB
    _Float16* Wt  = (_Float16*)p;  p += (size_t)L * D * D * 2;   // 1.57 MB
    float* src_norm = (float*)p;   p += (size_t)N * 4;
    float* dst_norm = (float*)p;   p += (size_t)N * 4;
    // contiguous zero-init region: out_deg, in_deg, stats0..2
    int* out_deg   = (int*)p;      p += (size_t)N * 4;
    int* in_deg    = (int*)p;      p += (size_t)N * 4;
    float* stats0  = (float*)p;    p += 2 * D * 4;
    float* stats1  = (float*)p;    p += 2 * D * 4;
    float* stats2  = (float*)p;    p += 2 * D * 4;
    int* csr_off   = (int*)p;      p += (size_t)(N + 1) * 4;
    int* cursor    = (int*)p;      p += (size_t)N * 4;
    int* csr_src   = (int*)p;      p += (size_t)E * 4;

    float* stats_in[3] = {stats0, stats1, stats2};

    // --- setup ---
    hipMemsetAsync(out_deg, 0, (2 * (size_t)N + 6 * D) * sizeof(int), stream);
    mega_setup<<<MEGA_BLOCKS, 256, 0, stream>>>(src, dst, x_in, W,
                                                out_deg, in_deg, x16, stats0, Wt);
    scan_indeg<<<1, 1024, 0, stream>>>(in_deg, out_deg, csr_off, cursor,
                                       src_norm, dst_norm);
    csr_fill<<<DEG_BLOCKS, 256, 0, stream>>>(src, dst, cursor, csr_src);

    dim3 mm_grid((N + 127) / 128, D / 128);
    const int agg_blocks = (N + 3) / 4;  // 4 waves per 256-thread block

    for (int l = 0; l < L; ++l) {
        const float* gl  = gamma + (size_t)l * D;
        const float* bl  = beta + (size_t)l * D;
        const _Float16* Wl = Wt + (size_t)l * D * D;
        const float* bil = b + (size_t)l * D;

        aggregate_bn<<<agg_blocks, 256, 0, stream>>>(
            x16, csr_off, csr_src, src_norm, dst_norm, stats_in[l], gl, bl, agg);
        if (l == L - 1) {
            mm_f16_relu<float, false><<<mm_grid, 256, 0, stream>>>(
                agg, Wl, bil, out, N, nullptr);
        } else {
            mm_f16_relu<_Float16, true><<<mm_grid, 256, 0, stream>>>(
                agg, Wl, bil, x16, N, stats_in[l + 1]);
        }
    }
}

// Round 7
// 317.636 us; speedup vs baseline: 1.1362x; 1.1362x over previous
//
#include <hip/hip_runtime.h>
#include <hip/hip_bf16.h>

constexpr int N = 10000;   // nodes
constexpr int D = 512;     // feature dim
constexpr int E = 160000;  // edges
constexpr int L = 3;       // layers
constexpr float EPS = 1e-5f;

typedef _Float16 half8 __attribute__((ext_vector_type(8)));
typedef _Float16 half2v __attribute__((ext_vector_type(2)));
typedef float floatx4 __attribute__((ext_vector_type(4)));

// async global->LDS, 16B per lane. LDS dest = wave-uniform base + lane*16.
__device__ __forceinline__ void glds16(const _Float16* g, _Float16* l) {
    __builtin_amdgcn_global_load_lds(
        (const __attribute__((address_space(1))) uint32_t*)(g),
        (__attribute__((address_space(3))) uint32_t*)(l),
        16, 0, 0);
}

// ---------------------------------------------------------------------------
// Mega setup: degrees + x fp32->f16 conversion + column stats + W transpose.
// conv rebalanced: 1000 blocks x 10 rows (was 100 x 100 -- kernel long pole).
// ---------------------------------------------------------------------------
constexpr int DEG_BLOCKS  = (E + 255) / 256;   // 625
constexpr int CONV_BLOCKS = 1000;              // 10 rows each
constexpr int TW_BLOCKS   = L * 256;           // 768 (32x32 tiles)
constexpr int MEGA_BLOCKS = DEG_BLOCKS + CONV_BLOCKS + TW_BLOCKS;

__global__ __launch_bounds__(256) void mega_setup(
    const int* __restrict__ src, const int* __restrict__ dst,
    const float* __restrict__ x, const float* __restrict__ W,
    int* __restrict__ out_deg, int* __restrict__ in_deg,
    _Float16* __restrict__ x16, float* __restrict__ stats0,
    _Float16* __restrict__ Wt) {
    __shared__ float tb[32][33];
    int bid = blockIdx.x;
    int tid = threadIdx.x;
    if (bid < DEG_BLOCKS) {
        int e = bid * 256 + tid;
        if (e < E) {
            atomicAdd(&out_deg[src[e]], 1);
            atomicAdd(&in_deg[dst[e]], 1);
        }
    } else if (bid < DEG_BLOCKS + CONV_BLOCKS) {
        int b = bid - DEG_BLOCKS;
        int r0 = b * 10;
        int r1 = r0 + 10; if (r1 > N) r1 = N;
        int c2 = tid * 2;
        float s0 = 0.f, s1 = 0.f, q0 = 0.f, q1 = 0.f;
        for (int r = r0; r < r1; ++r) {
            float2 v = *(const float2*)(x + (size_t)r * D + c2);
            s0 += v.x; q0 += v.x * v.x;
            s1 += v.y; q1 += v.y * v.y;
            half2v h; h[0] = (_Float16)v.x; h[1] = (_Float16)v.y;
            *(half2v*)(x16 + (size_t)r * D + c2) = h;
        }
        atomicAdd(&stats0[c2], s0);
        atomicAdd(&stats0[c2 + 1], s1);
        atomicAdd(&stats0[D + c2], q0);
        atomicAdd(&stats0[D + c2 + 1], q1);
    } else {
        int b = bid - DEG_BLOCKS - CONV_BLOCKS;  // 0..767
        int l = b >> 8;
        int t = b & 255;
        int k0 = (t >> 4) * 32, n0 = (t & 15) * 32;
        int tx = tid & 31, ty = tid >> 5;  // 32 x 8
        const float* Wl = W + (size_t)l * D * D;
        _Float16* Wtl = Wt + (size_t)l * D * D;
        for (int i = 0; i < 32; i += 8)
            tb[ty + i][tx] = Wl[(size_t)(k0 + ty + i) * D + n0 + tx];
        __syncthreads();
        for (int i = 0; i < 32; i += 8)
            Wtl[(size_t)(n0 + ty + i) * D + k0 + tx] = (_Float16)tb[tx][ty + i];
    }
}

// ---------------------------------------------------------------------------
// Single block: exclusive scan of in_deg -> off & cursor, plus both norms.
// ---------------------------------------------------------------------------
__global__ void scan_indeg(const int* __restrict__ in_deg,
                           const int* __restrict__ out_deg,
                           int* __restrict__ off, int* __restrict__ cursor,
                           float* __restrict__ src_norm, float* __restrict__ dst_norm) {
    __shared__ int lsum[1024];
    int t = threadIdx.x;
    const int chunk = (N + 1023) / 1024;
    int start = t * chunk;
    int end = start + chunk; if (end > N) end = N;
    int s = 0;
    for (int i = start; i < end; ++i) s += in_deg[i];
    lsum[t] = s;
    __syncthreads();
    for (int d = 1; d < 1024; d <<= 1) {
        int v = (t >= d) ? lsum[t - d] : 0;
        __syncthreads();
        lsum[t] += v;
        __syncthreads();
    }
    int excl = (t == 0) ? 0 : lsum[t - 1];
    for (int i = start; i < end; ++i) {
        off[i] = excl;
        cursor[i] = excl;
        excl += in_deg[i];
        int od = out_deg[i]; if (od < 1) od = 1;
        int id = in_deg[i];  if (id < 1) id = 1;
        src_norm[i] = rsqrtf((float)od);
        dst_norm[i] = rsqrtf((float)id);
    }
    if (t == 1023) off[N] = lsum[1023];
}

__global__ void csr_fill(const int* __restrict__ src, const int* __restrict__ dst,
                         int* __restrict__ cursor, int* __restrict__ csr_src) {
    int e = blockIdx.x * blockDim.x + threadIdx.x;
    if (e >= E) return;
    int d = dst[e];
    int pos = atomicAdd(&cursor[d], 1);
    csr_src[pos] = src[e];
}

// ---------------------------------------------------------------------------
// Fused BN + gather-aggregate, coef in-register from stats. One wave per node.
// 4x edge unroll: 4 independent 1KB row loads in flight per iteration.
// (round-1 verified, unchanged)
// ---------------------------------------------------------------------------
__global__ __launch_bounds__(256) void aggregate_bn(
    const _Float16* __restrict__ x, const int* __restrict__ off,
    const int* __restrict__ csr_src, const float* __restrict__ src_norm,
    const float* __restrict__ dst_norm, const float* __restrict__ stats,
    const float* __restrict__ gamma, const float* __restrict__ beta,
    _Float16* __restrict__ agg) {
    int wid = (blockIdx.x * 256 + threadIdx.x) >> 6;
    if (wid >= N) return;
    int lane = threadIdx.x & 63;
    int c0 = lane * 8;

    float scale[8], shift[8];
    const float invN = 1.0f / (float)N;
    for (int i = 0; i < 8; ++i) {
        int c = c0 + i;
        float mu = stats[c] * invN;
        float var = stats[D + c] * invN - mu * mu;
        float sc = gamma[c] * rsqrtf(var + EPS);
        scale[i] = sc;
        shift[i] = beta[c] - mu * sc;
    }

    int e0 = off[wid], e1 = off[wid + 1];
    float a[8] = {}, a2[8] = {};
    float t = 0.f;
    int e = e0;
    for (; e + 4 <= e1; e += 4) {
        int s0 = csr_src[e];
        int s1 = csr_src[e + 1];
        int s2 = csr_src[e + 2];
        int s3 = csr_src[e + 3];
        float n0 = src_norm[s0];
        float n1 = src_norm[s1];
        float n2 = src_norm[s2];
        float n3 = src_norm[s3];
        half8 v0 = *(const half8*)(x + (size_t)s0 * D + c0);
        half8 v1 = *(const half8*)(x + (size_t)s1 * D + c0);
        half8 v2 = *(const half8*)(x + (size_t)s2 * D + c0);
        half8 v3 = *(const half8*)(x + (size_t)s3 * D + c0);
        t += (n0 + n1) + (n2 + n3);
        for (int k = 0; k < 8; ++k) {
            a[k]  += (float)v0[k] * n0;
            a2[k] += (float)v1[k] * n1;
            a[k]  += (float)v2[k] * n2;
            a2[k] += (float)v3[k] * n3;
        }
    }
    for (; e < e1; ++e) {
        int s0 = csr_src[e];
        float n0 = src_norm[s0];
        half8 v0 = *(const half8*)(x + (size_t)s0 * D + c0);
        t += n0;
        for (int k = 0; k < 8; ++k) a[k] += (float)v0[k] * n0;
    }
    float dn = dst_norm[wid];
    half8 o;
    for (int i = 0; i < 8; ++i)
        o[i] = (_Float16)(dn * (scale[i] * (a[i] + a2[i]) + shift[i] * t));
    *(half8*)(agg + (size_t)wid * D + c0) = o;
}

// ---------------------------------------------------------------------------
// C = relu(A @ W + bias) via f16 MFMA.  (round-2 correctness-proven version)
// Tile 64(M) x 128(N), BK=64, block = 128 threads (2 waves) -> 628 blocks,
// 2.45 blocks/CU for cross-block latency hiding (vs 316 at 128x128).
// Double-buffered LDS 2-phase pipeline + XOR chunk-swizzle (pre-swizzled
// global source, same involution on ds_read).
// ---------------------------------------------------------------------------
template <typename OutT, bool STATS>
__global__ __launch_bounds__(128) void mm_f16_relu(
    const _Float16* __restrict__ A, const _Float16* __restrict__ Bt,
    const float* __restrict__ bias, OutT* __restrict__ C, int M,
    float* __restrict__ stats) {
    __shared__ __align__(16) _Float16 As[2][64 * 64];    // 16 KB
    __shared__ __align__(16) _Float16 Bs[2][128 * 64];   // 32 KB
    const int tid  = threadIdx.x;
    const int wave = tid >> 6;
    const int lane = tid & 63;
    const int quad = lane >> 4;
    const int l16  = lane & 15;
    const int row0 = blockIdx.x * 64;
    const int col0 = blockIdx.y * 128;
    const int wn   = wave * 64;

    // staging lane map: 8 rows x 8 chunks of 16B per wave-glds (1 KB slab)
    const int srl = lane >> 3;          // row within slab 0..7
    const int sq  = lane & 7;           // dest chunk 0..7
    const int sqs = (sq ^ srl) * 8;     // pre-swizzled source col (f16 units)

    const _Float16* gA[4];
    const _Float16* gB[8];
#pragma unroll
    for (int j = 0; j < 4; ++j) {
        int ar = row0 + wave * 32 + j * 8 + srl;
        if (ar >= M) ar = M - 1;
        gA[j] = A + (size_t)ar * D + sqs;
    }
#pragma unroll
    for (int j = 0; j < 8; ++j) {
        int br = col0 + wave * 64 + j * 8 + srl;
        gB[j] = Bt + (size_t)br * D + sqs;
    }

    // read-side swizzled chunk offsets (f16 units); row&7 == l16&7 here
    const int l7 = l16 & 7;
    const int swz0 = (quad ^ l7) * 8;        // kk=0: chunk = quad
    const int swz1 = ((4 + quad) ^ l7) * 8;  // kk=1: chunk = 4+quad

    floatx4 acc[4][4] = {};

    auto stage = [&](int buf, int k0) {
        _Float16* as = As[buf] + (wave * 32) * 64;
        _Float16* bs = Bs[buf] + (wave * 64) * 64;
#pragma unroll
        for (int j = 0; j < 4; ++j)
            glds16(gA[j] + k0, as + j * 8 * 64);
#pragma unroll
        for (int j = 0; j < 8; ++j)
            glds16(gB[j] + k0, bs + j * 8 * 64);
    };

    stage(0, 0);
    __syncthreads();  // compiler drains vmcnt before barrier

    int cur = 0;
    for (int kt = 0; kt < 8; ++kt) {
        if (kt < 7) stage(cur ^ 1, (kt + 1) * 64);
        const _Float16* asb = As[cur];
        const _Float16* bsb = Bs[cur];
        half8 af0[4], af1[4], bf0[4], bf1[4];
#pragma unroll
        for (int i = 0; i < 4; ++i) {
            int r = i * 16 + l16;
            af0[i] = *(const half8*)(asb + r * 64 + swz0);
            af1[i] = *(const half8*)(asb + r * 64 + swz1);
        }
#pragma unroll
        for (int j = 0; j < 4; ++j) {
            int r = wn + j * 16 + l16;
            bf0[j] = *(const half8*)(bsb + r * 64 + swz0);
            bf1[j] = *(const half8*)(bsb + r * 64 + swz1);
        }
#pragma unroll
        for (int i = 0; i < 4; ++i)
#pragma unroll
            for (int j = 0; j < 4; ++j)
                acc[i][j] = __builtin_amdgcn_mfma_f32_16x16x32_f16(
                    af0[i], bf0[j], acc[i][j], 0, 0, 0);
#pragma unroll
        for (int i = 0; i < 4; ++i)
#pragma unroll
            for (int j = 0; j < 4; ++j)
                acc[i][j] = __builtin_amdgcn_mfma_f32_16x16x32_f16(
                    af1[i], bf1[j], acc[i][j], 0, 0, 0);
        __syncthreads();  // drains staged loads + joins waves
        cur ^= 1;
    }

    // epilogue: C/D layout col = lane&15, row = quad*4 + reg
    float s[4] = {}, q[4] = {};
#pragma unroll
    for (int i = 0; i < 4; ++i) {
#pragma unroll
        for (int r = 0; r < 4; ++r) {
            int row = row0 + i * 16 + quad * 4 + r;
            bool valid = row < M;
#pragma unroll
            for (int j = 0; j < 4; ++j) {
                int col = col0 + wn + j * 16 + l16;
                float v = acc[i][j][r] + bias[col];
                v = v > 0.f ? v : 0.f;
                if (valid) {
                    C[(size_t)row * D + col] = (OutT)v;
                    if (STATS) { s[j] += v; q[j] += v * v; }
                }
            }
        }
    }
    if (STATS) {
#pragma unroll
        for (int j = 0; j < 4; ++j) {
            float sv = s[j], qv = q[j];
            sv += __shfl_xor(sv, 16); sv += __shfl_xor(sv, 32);
            qv += __shfl_xor(qv, 16); qv += __shfl_xor(qv, 32);
            if (quad == 0) {
                int col = col0 + wn + j * 16 + l16;
                atomicAdd(&stats[col], sv);
                atomicAdd(&stats[D + col], qv);
            }
        }
    }
}

// ---------------------------------------------------------------------------
extern "C" void kernel_launch(void* const* d_in, const int* in_sizes, int n_in,
                              void* d_out, int out_size, void* d_ws, size_t ws_size,
                              hipStream_t stream) {
    const float* x_in  = (const float*)d_in[0];
    const int*   src   = (const int*)d_in[1];
    const int*   dst   = (const int*)d_in[2];
    const float* gamma = (const float*)d_in[3];
    const float* beta  = (const float*)d_in[4];
    const float* W     = (const float*)d_in[5];
    const float* b     = (const float*)d_in[6];
    float* out = (float*)d_out;

    // workspace carve-up (16B-aligned segments first)
    char* p = (char*)d_ws;
    _Float16* x16 = (_Float16*)p;  p += (size_t)N * D * 2;       // 10.24 MB
    _Float16* agg = (_Float16*)p;  p += (size_t)N * D * 2;       // 10.24 MB
    _Float16* Wt  = (_Float16*)p;  p += (size_t)L * D * D * 2;   // 1.57 MB
    float* src_norm = (float*)p;   p += (size_t)N * 4;
    float* dst_norm = (float*)p;   p += (size_t)N * 4;
    // contiguous zero-init region: out_deg, in_deg, stats0..2
    int* out_deg   = (int*)p;      p += (size_t)N * 4;
    int* in_deg    = (int*)p;      p += (size_t)N * 4;
    float* stats0  = (float*)p;    p += 2 * D * 4;
    float* stats1  = (float*)p;    p += 2 * D * 4;
    float* stats2  = (float*)p;    p += 2 * D * 4;
    int* csr_off   = (int*)p;      p += (size_t)(N + 1) * 4;
    int* cursor    = (int*)p;      p += (size_t)N * 4;
    int* csr_src   = (int*)p;      p += (size_t)E * 4;

    float* stats_in[3] = {stats0, stats1, stats2};

    // --- setup ---
    hipMemsetAsync(out_deg, 0, (2 * (size_t)N + 6 * D) * sizeof(int), stream);
    mega_setup<<<MEGA_BLOCKS, 256, 0, stream>>>(src, dst, x_in, W,
                                                out_deg, in_deg, x16, stats0, Wt);
    scan_indeg<<<1, 1024, 0, stream>>>(in_deg, out_deg, csr_off, cursor,
                                       src_norm, dst_norm);
    csr_fill<<<DEG_BLOCKS, 256, 0, stream>>>(src, dst, cursor, csr_src);

    dim3 mm_grid((N + 63) / 64, D / 128);  // 157 x 4 = 628 blocks
    const int agg_blocks = (N + 3) / 4;    // 4 waves per 256-thread block

    for (int l = 0; l < L; ++l) {
        const float* gl  = gamma + (size_t)l * D;
        const float* bl  = beta + (size_t)l * D;
        const _Float16* Wl = Wt + (size_t)l * D * D;
        const float* bil = b + (size_t)l * D;

        aggregate_bn<<<agg_blocks, 256, 0, stream>>>(
            x16, csr_off, csr_src, src_norm, dst_norm, stats_in[l], gl, bl, agg);
        if (l == L - 1) {
            mm_f16_relu<float, false><<<mm_grid, 128, 0, stream>>>(
                agg, Wl, bil, out, N, nullptr);
        } else {
            mm_f16_relu<_Float16, true><<<mm_grid, 128, 0, stream>>>(
                agg, Wl, bil, x16, N, stats_in[l + 1]);
        }
    }
}

// Round 8
// 283.906 us; speedup vs baseline: 1.2712x; 1.1188x over previous
//
#include <hip/hip_runtime.h>
#include <hip/hip_bf16.h>

constexpr int N = 10000;   // nodes
constexpr int D = 512;     // feature dim
constexpr int E = 160000;  // edges
constexpr int L = 3;       // layers
constexpr float EPS = 1e-5f;

typedef _Float16 half8 __attribute__((ext_vector_type(8)));
typedef _Float16 half2v __attribute__((ext_vector_type(2)));
typedef float floatx4 __attribute__((ext_vector_type(4)));

// async global->LDS, 16B per lane. LDS dest = wave-uniform base + lane*16.
__device__ __forceinline__ void glds16(const _Float16* g, _Float16* l) {
    __builtin_amdgcn_global_load_lds(
        (const __attribute__((address_space(1))) uint32_t*)(g),
        (__attribute__((address_space(3))) uint32_t*)(l),
        16, 0, 0);
}

// ---------------------------------------------------------------------------
// Mega setup: x fp32->f16 conversion + column stats FIRST (long pole, 250
// blocks x 40 rows -- atomic chains/addr = 250, vs 1000 which serialized),
// then degrees, then W transpose.
// ---------------------------------------------------------------------------
constexpr int CONV_BLOCKS = 250;               // 40 rows each, dispatched first
constexpr int DEG_BLOCKS  = (E + 255) / 256;   // 625
constexpr int TW_BLOCKS   = L * 256;           // 768 (32x32 tiles)
constexpr int MEGA_BLOCKS = CONV_BLOCKS + DEG_BLOCKS + TW_BLOCKS;

__global__ __launch_bounds__(256) void mega_setup(
    const int* __restrict__ src, const int* __restrict__ dst,
    const float* __restrict__ x, const float* __restrict__ W,
    int* __restrict__ out_deg, int* __restrict__ in_deg,
    _Float16* __restrict__ x16, float* __restrict__ stats0,
    _Float16* __restrict__ Wt) {
    __shared__ float tb[32][33];
    int bid = blockIdx.x;
    int tid = threadIdx.x;
    if (bid < CONV_BLOCKS) {
        int r0 = bid * 40;
        int r1 = r0 + 40; if (r1 > N) r1 = N;
        int c2 = tid * 2;
        float s0 = 0.f, s1 = 0.f, q0 = 0.f, q1 = 0.f;
        for (int r = r0; r < r1; ++r) {
            float2 v = *(const float2*)(x + (size_t)r * D + c2);
            s0 += v.x; q0 += v.x * v.x;
            s1 += v.y; q1 += v.y * v.y;
            half2v h; h[0] = (_Float16)v.x; h[1] = (_Float16)v.y;
            *(half2v*)(x16 + (size_t)r * D + c2) = h;
        }
        atomicAdd(&stats0[c2], s0);
        atomicAdd(&stats0[c2 + 1], s1);
        atomicAdd(&stats0[D + c2], q0);
        atomicAdd(&stats0[D + c2 + 1], q1);
    } else if (bid < CONV_BLOCKS + DEG_BLOCKS) {
        int e = (bid - CONV_BLOCKS) * 256 + tid;
        if (e < E) {
            atomicAdd(&out_deg[src[e]], 1);
            atomicAdd(&in_deg[dst[e]], 1);
        }
    } else {
        int b = bid - CONV_BLOCKS - DEG_BLOCKS;  // 0..767
        int l = b >> 8;
        int t = b & 255;
        int k0 = (t >> 4) * 32, n0 = (t & 15) * 32;
        int tx = tid & 31, ty = tid >> 5;  // 32 x 8
        const float* Wl = W + (size_t)l * D * D;
        _Float16* Wtl = Wt + (size_t)l * D * D;
        for (int i = 0; i < 32; i += 8)
            tb[ty + i][tx] = Wl[(size_t)(k0 + ty + i) * D + n0 + tx];
        __syncthreads();
        for (int i = 0; i < 32; i += 8)
            Wtl[(size_t)(n0 + ty + i) * D + k0 + tx] = (_Float16)tb[tx][ty + i];
    }
}

// ---------------------------------------------------------------------------
// Single block: exclusive scan of in_deg -> off & cursor. (norms moved to
// csr_fill -- they only need degrees, not the scan.)
// ---------------------------------------------------------------------------
__global__ void scan_indeg(const int* __restrict__ in_deg,
                           int* __restrict__ off, int* __restrict__ cursor) {
    __shared__ int lsum[1024];
    int t = threadIdx.x;
    const int chunk = (N + 1023) / 1024;
    int start = t * chunk;
    int end = start + chunk; if (end > N) end = N;
    int s = 0;
    for (int i = start; i < end; ++i) s += in_deg[i];
    lsum[t] = s;
    __syncthreads();
    for (int d = 1; d < 1024; d <<= 1) {
        int v = (t >= d) ? lsum[t - d] : 0;
        __syncthreads();
        lsum[t] += v;
        __syncthreads();
    }
    int excl = (t == 0) ? 0 : lsum[t - 1];
    for (int i = start; i < end; ++i) {
        off[i] = excl;
        cursor[i] = excl;
        excl += in_deg[i];
    }
    if (t == 1023) off[N] = lsum[1023];
}

// ---------------------------------------------------------------------------
// csr fill + parallel norm computation (appended blocks).
// ---------------------------------------------------------------------------
constexpr int NORM_BLOCKS = (N + 255) / 256;  // 40
__global__ void csr_fill(const int* __restrict__ src, const int* __restrict__ dst,
                         int* __restrict__ cursor, int* __restrict__ csr_src,
                         const int* __restrict__ in_deg, const int* __restrict__ out_deg,
                         float* __restrict__ src_norm, float* __restrict__ dst_norm) {
    int bid = blockIdx.x;
    if (bid < DEG_BLOCKS) {
        int e = bid * 256 + threadIdx.x;
        if (e >= E) return;
        int d = dst[e];
        int pos = atomicAdd(&cursor[d], 1);
        csr_src[pos] = src[e];
    } else {
        int i = (bid - DEG_BLOCKS) * 256 + threadIdx.x;
        if (i >= N) return;
        int od = out_deg[i]; if (od < 1) od = 1;
        int id = in_deg[i];  if (id < 1) id = 1;
        src_norm[i] = rsqrtf((float)od);
        dst_norm[i] = rsqrtf((float)id);
    }
}

// ---------------------------------------------------------------------------
// Fused BN + gather-aggregate, coef in-register from stats. One wave per node.
// 4x edge unroll: 4 independent 1KB row loads in flight per iteration.
// (round-1 verified, unchanged)
// ---------------------------------------------------------------------------
__global__ __launch_bounds__(256) void aggregate_bn(
    const _Float16* __restrict__ x, const int* __restrict__ off,
    const int* __restrict__ csr_src, const float* __restrict__ src_norm,
    const float* __restrict__ dst_norm, const float* __restrict__ stats,
    const float* __restrict__ gamma, const float* __restrict__ beta,
    _Float16* __restrict__ agg) {
    int wid = (blockIdx.x * 256 + threadIdx.x) >> 6;
    if (wid >= N) return;
    int lane = threadIdx.x & 63;
    int c0 = lane * 8;

    float scale[8], shift[8];
    const float invN = 1.0f / (float)N;
    for (int i = 0; i < 8; ++i) {
        int c = c0 + i;
        float mu = stats[c] * invN;
        float var = stats[D + c] * invN - mu * mu;
        float sc = gamma[c] * rsqrtf(var + EPS);
        scale[i] = sc;
        shift[i] = beta[c] - mu * sc;
    }

    int e0 = off[wid], e1 = off[wid + 1];
    float a[8] = {}, a2[8] = {};
    float t = 0.f;
    int e = e0;
    for (; e + 4 <= e1; e += 4) {
        int s0 = csr_src[e];
        int s1 = csr_src[e + 1];
        int s2 = csr_src[e + 2];
        int s3 = csr_src[e + 3];
        float n0 = src_norm[s0];
        float n1 = src_norm[s1];
        float n2 = src_norm[s2];
        float n3 = src_norm[s3];
        half8 v0 = *(const half8*)(x + (size_t)s0 * D + c0);
        half8 v1 = *(const half8*)(x + (size_t)s1 * D + c0);
        half8 v2 = *(const half8*)(x + (size_t)s2 * D + c0);
        half8 v3 = *(const half8*)(x + (size_t)s3 * D + c0);
        t += (n0 + n1) + (n2 + n3);
        for (int k = 0; k < 8; ++k) {
            a[k]  += (float)v0[k] * n0;
            a2[k] += (float)v1[k] * n1;
            a[k]  += (float)v2[k] * n2;
            a2[k] += (float)v3[k] * n3;
        }
    }
    for (; e < e1; ++e) {
        int s0 = csr_src[e];
        float n0 = src_norm[s0];
        half8 v0 = *(const half8*)(x + (size_t)s0 * D + c0);
        t += n0;
        for (int k = 0; k < 8; ++k) a[k] += (float)v0[k] * n0;
    }
    float dn = dst_norm[wid];
    half8 o;
    for (int i = 0; i < 8; ++i)
        o[i] = (_Float16)(dn * (scale[i] * (a[i] + a2[i]) + shift[i] * t));
    *(half8*)(agg + (size_t)wid * D + c0) = o;
}

// ---------------------------------------------------------------------------
// C = relu(A @ W + bias) via f16 MFMA -- v3.
// r1's proven geometry (128x128 tile, 4 waves, wave = 64x64 of 4x4
// mfma_f32_16x16x32_f16, same K order) with:
//   BK=64, double-buffered LDS (2x32KB), 2-phase stage-before-compute,
//   8-chunk XOR swizzle (pre-swizzled glds source + same involution on
//   ds_read) -> 2-way bank access (free) vs r1's 8-way conflict.
// ---------------------------------------------------------------------------
template <typename OutT, bool STATS>
__global__ __launch_bounds__(256) void mm_f16_relu(
    const _Float16* __restrict__ A, const _Float16* __restrict__ Bt,
    const float* __restrict__ bias, OutT* __restrict__ C, int M,
    float* __restrict__ stats) {
    __shared__ __align__(16) _Float16 As[2][128 * 64];   // 16 KB each
    __shared__ __align__(16) _Float16 Bs[2][128 * 64];
    const int tid  = threadIdx.x;
    const int wave = tid >> 6;
    const int lane = tid & 63;
    const int quad = lane >> 4;
    const int l16  = lane & 15;
    const int row0 = blockIdx.x * 128;
    const int col0 = blockIdx.y * 128;
    const int wm = (wave & 1) * 64;
    const int wn = (wave >> 1) * 64;

    // staging: per wave 4 glds for A + 4 for B, each 8 rows x 128B = 1KB.
    const int srl = lane >> 3;          // row-in-slab 0..7
    const int sq  = lane & 7;           // dest chunk 0..7
    const int sqs = (sq ^ srl) * 8;     // pre-swizzled source col (halves)

    const _Float16* gA[4];
    const _Float16* gB[4];
#pragma unroll
    for (int j = 0; j < 4; ++j) {
        int ar = row0 + wave * 32 + j * 8 + srl;
        if (ar >= M) ar = M - 1;
        gA[j] = A + (size_t)ar * D + sqs;
        int br = col0 + wave * 32 + j * 8 + srl;
        gB[j] = Bt + (size_t)br * D + sqs;
    }

    // read-side swizzled chunk offsets (halves); row&7 == l16&7 for all frags
    const int l7 = l16 & 7;
    const int swz0 = (quad ^ l7) * 8;        // k-halves 0..31  (chunk quad)
    const int swz1 = ((4 + quad) ^ l7) * 8;  // k-halves 32..63 (chunk 4+quad)

    floatx4 acc[4][4] = {};

    auto stage = [&](int buf, int k0) {
        _Float16* as = As[buf] + (wave * 32) * 64;
        _Float16* bs = Bs[buf] + (wave * 32) * 64;
#pragma unroll
        for (int j = 0; j < 4; ++j) {
            glds16(gA[j] + k0, as + j * 8 * 64);
            glds16(gB[j] + k0, bs + j * 8 * 64);
        }
    };

    stage(0, 0);
    __syncthreads();  // vmcnt(0) drain + join

    int cur = 0;
    for (int kt = 0; kt < 8; ++kt) {
        if (kt < 7) stage(cur ^ 1, (kt + 1) * 64);  // prefetch hides under compute
        const _Float16* asb = As[cur];
        const _Float16* bsb = Bs[cur];
        half8 af0[4], af1[4], bf0[4], bf1[4];
#pragma unroll
        for (int i = 0; i < 4; ++i) {
            int r = wm + i * 16 + l16;
            af0[i] = *(const half8*)(asb + r * 64 + swz0);
            af1[i] = *(const half8*)(asb + r * 64 + swz1);
        }
#pragma unroll
        for (int j = 0; j < 4; ++j) {
            int r = wn + j * 16 + l16;
            bf0[j] = *(const half8*)(bsb + r * 64 + swz0);
            bf1[j] = *(const half8*)(bsb + r * 64 + swz1);
        }
#pragma unroll
        for (int i = 0; i < 4; ++i)
#pragma unroll
            for (int j = 0; j < 4; ++j)
                acc[i][j] = __builtin_amdgcn_mfma_f32_16x16x32_f16(
                    af0[i], bf0[j], acc[i][j], 0, 0, 0);
#pragma unroll
        for (int i = 0; i < 4; ++i)
#pragma unroll
            for (int j = 0; j < 4; ++j)
                acc[i][j] = __builtin_amdgcn_mfma_f32_16x16x32_f16(
                    af1[i], bf1[j], acc[i][j], 0, 0, 0);
        __syncthreads();  // drains prefetch + joins waves
        cur ^= 1;
    }

    // epilogue: C/D layout col = lane&15, row = quad*4 + reg (r1-identical)
    float s[4] = {}, q[4] = {};
    for (int i = 0; i < 4; ++i) {
        for (int r = 0; r < 4; ++r) {
            int row = row0 + wm + i * 16 + quad * 4 + r;
            bool valid = row < M;
            for (int j = 0; j < 4; ++j) {
                int col = col0 + wn + j * 16 + l16;
                float v = acc[i][j][r] + bias[col];
                v = v > 0.f ? v : 0.f;
                if (valid) {
                    C[(size_t)row * D + col] = (OutT)v;
                    if (STATS) { s[j] += v; q[j] += v * v; }
                }
            }
        }
    }
    if (STATS) {
        for (int j = 0; j < 4; ++j) {
            float sv = s[j], qv = q[j];
            sv += __shfl_xor(sv, 16); sv += __shfl_xor(sv, 32);
            qv += __shfl_xor(qv, 16); qv += __shfl_xor(qv, 32);
            if (quad == 0) {
                int col = col0 + wn + j * 16 + l16;
                atomicAdd(&stats[col], sv);
                atomicAdd(&stats[D + col], qv);
            }
        }
    }
}

// ---------------------------------------------------------------------------
extern "C" void kernel_launch(void* const* d_in, const int* in_sizes, int n_in,
                              void* d_out, int out_size, void* d_ws, size_t ws_size,
                              hipStream_t stream) {
    const float* x_in  = (const float*)d_in[0];
    const int*   src   = (const int*)d_in[1];
    const int*   dst   = (const int*)d_in[2];
    const float* gamma = (const float*)d_in[3];
    const float* beta  = (const float*)d_in[4];
    const float* W     = (const float*)d_in[5];
    const float* b     = (const float*)d_in[6];
    float* out = (float*)d_out;

    // workspace carve-up (16B-aligned segments first)
    char* p = (char*)d_ws;
    _Float16* x16 = (_Float16*)p;  p += (size_t)N * D * 2;       // 10.24 MB
    _Float16* agg = (_Float16*)p;  p += (size_t)N * D * 2;       // 10.24 MB
    _Float16* Wt  = (_Float16*)p;  p += (size_t)L * D * D * 2;   // 1.57 MB
    float* src_norm = (float*)p;   p += (size_t)N * 4;
    float* dst_norm = (float*)p;   p += (size_t)N * 4;
    // contiguous zero-init region: out_deg, in_deg, stats0..2
    int* out_deg   = (int*)p;      p += (size_t)N * 4;
    int* in_deg    = (int*)p;      p += (size_t)N * 4;
    float* stats0  = (float*)p;    p += 2 * D * 4;
    float* stats1  = (float*)p;    p += 2 * D * 4;
    float* stats2  = (float*)p;    p += 2 * D * 4;
    int* csr_off   = (int*)p;      p += (size_t)(N + 1) * 4;
    int* cursor    = (int*)p;      p += (size_t)N * 4;
    int* csr_src   = (int*)p;      p += (size_t)E * 4;

    float* stats_in[3] = {stats0, stats1, stats2};

    // --- setup ---
    hipMemsetAsync(out_deg, 0, (2 * (size_t)N + 6 * D) * sizeof(int), stream);
    mega_setup<<<MEGA_BLOCKS, 256, 0, stream>>>(src, dst, x_in, W,
                                                out_deg, in_deg, x16, stats0, Wt);
    scan_indeg<<<1, 1024, 0, stream>>>(in_deg, csr_off, cursor);
    csr_fill<<<DEG_BLOCKS + NORM_BLOCKS, 256, 0, stream>>>(
        src, dst, cursor, csr_src, in_deg, out_deg, src_norm, dst_norm);

    dim3 mm_grid((N + 127) / 128, D / 128);
    const int agg_blocks = (N + 3) / 4;  // 4 waves per 256-thread block

    for (int l = 0; l < L; ++l) {
        const float* gl  = gamma + (size_t)l * D;
        const float* bl  = beta + (size_t)l * D;
        const _Float16* Wl = Wt + (size_t)l * D * D;
        const float* bil = b + (size_t)l * D;

        aggregate_bn<<<agg_blocks, 256, 0, stream>>>(
            x16, csr_off, csr_src, src_norm, dst_norm, stats_in[l], gl, bl, agg);
        if (l == L - 1) {
            mm_f16_relu<float, false><<<mm_grid, 256, 0, stream>>>(
                agg, Wl, bil, out, N, nullptr);
        } else {
            mm_f16_relu<_Float16, true><<<mm_grid, 256, 0, stream>>>(
                agg, Wl, bil, x16, N, stats_in[l + 1]);
        }
    }
}

// Round 9
// 281.260 us; speedup vs baseline: 1.2831x; 1.0094x over previous
//
#include <hip/hip_runtime.h>
#include <hip/hip_bf16.h>

constexpr int N = 10000;   // nodes
constexpr int D = 512;     // feature dim
constexpr int E = 160000;  // edges
constexpr int L = 3;       // layers
constexpr float EPS = 1e-5f;

typedef _Float16 half8 __attribute__((ext_vector_type(8)));
typedef _Float16 half2v __attribute__((ext_vector_type(2)));
typedef float floatx4 __attribute__((ext_vector_type(4)));

// async global->LDS, 16B per lane. LDS dest = wave-uniform base + lane*16.
__device__ __forceinline__ void glds16(const _Float16* g, _Float16* l) {
    __builtin_amdgcn_global_load_lds(
        (const __attribute__((address_space(1))) uint32_t*)(g),
        (__attribute__((address_space(3))) uint32_t*)(l),
        16, 0, 0);
}

// ---------------------------------------------------------------------------
// Mega setup: x fp32->f16 conversion + column stats FIRST (long pole, 250
// blocks x 40 rows), then degrees, then W transpose.  (R8-proven)
// ---------------------------------------------------------------------------
constexpr int CONV_BLOCKS = 250;               // 40 rows each, dispatched first
constexpr int DEG_BLOCKS  = (E + 255) / 256;   // 625
constexpr int TW_BLOCKS   = L * 256;           // 768 (32x32 tiles)
constexpr int MEGA_BLOCKS = CONV_BLOCKS + DEG_BLOCKS + TW_BLOCKS;

__global__ __launch_bounds__(256) void mega_setup(
    const int* __restrict__ src, const int* __restrict__ dst,
    const float* __restrict__ x, const float* __restrict__ W,
    int* __restrict__ out_deg, int* __restrict__ in_deg,
    _Float16* __restrict__ x16, float* __restrict__ stats0,
    _Float16* __restrict__ Wt) {
    __shared__ float tb[32][33];
    int bid = blockIdx.x;
    int tid = threadIdx.x;
    if (bid < CONV_BLOCKS) {
        int r0 = bid * 40;
        int r1 = r0 + 40; if (r1 > N) r1 = N;
        int c2 = tid * 2;
        float s0 = 0.f, s1 = 0.f, q0 = 0.f, q1 = 0.f;
        for (int r = r0; r < r1; ++r) {
            float2 v = *(const float2*)(x + (size_t)r * D + c2);
            s0 += v.x; q0 += v.x * v.x;
            s1 += v.y; q1 += v.y * v.y;
            half2v h; h[0] = (_Float16)v.x; h[1] = (_Float16)v.y;
            *(half2v*)(x16 + (size_t)r * D + c2) = h;
        }
        atomicAdd(&stats0[c2], s0);
        atomicAdd(&stats0[c2 + 1], s1);
        atomicAdd(&stats0[D + c2], q0);
        atomicAdd(&stats0[D + c2 + 1], q1);
    } else if (bid < CONV_BLOCKS + DEG_BLOCKS) {
        int e = (bid - CONV_BLOCKS) * 256 + tid;
        if (e < E) {
            atomicAdd(&out_deg[src[e]], 1);
            atomicAdd(&in_deg[dst[e]], 1);
        }
    } else {
        int b = bid - CONV_BLOCKS - DEG_BLOCKS;  // 0..767
        int l = b >> 8;
        int t = b & 255;
        int k0 = (t >> 4) * 32, n0 = (t & 15) * 32;
        int tx = tid & 31, ty = tid >> 5;  // 32 x 8
        const float* Wl = W + (size_t)l * D * D;
        _Float16* Wtl = Wt + (size_t)l * D * D;
        for (int i = 0; i < 32; i += 8)
            tb[ty + i][tx] = Wl[(size_t)(k0 + ty + i) * D + n0 + tx];
        __syncthreads();
        for (int i = 0; i < 32; i += 8)
            Wtl[(size_t)(n0 + ty + i) * D + k0 + tx] = (_Float16)tb[tx][ty + i];
    }
}

// ---------------------------------------------------------------------------
// Single block: exclusive scan of in_deg -> off & cursor, plus both norms
// (norms computed here so csr_fill can READ src_norm race-free).
// ---------------------------------------------------------------------------
__global__ void scan_indeg(const int* __restrict__ in_deg,
                           const int* __restrict__ out_deg,
                           int* __restrict__ off, int* __restrict__ cursor,
                           float* __restrict__ src_norm, float* __restrict__ dst_norm) {
    __shared__ int lsum[1024];
    int t = threadIdx.x;
    const int chunk = (N + 1023) / 1024;
    int start = t * chunk;
    int end = start + chunk; if (end > N) end = N;
    int s = 0;
    for (int i = start; i < end; ++i) s += in_deg[i];
    lsum[t] = s;
    __syncthreads();
    for (int d = 1; d < 1024; d <<= 1) {
        int v = (t >= d) ? lsum[t - d] : 0;
        __syncthreads();
        lsum[t] += v;
        __syncthreads();
    }
    int excl = (t == 0) ? 0 : lsum[t - 1];
    for (int i = start; i < end; ++i) {
        off[i] = excl;
        cursor[i] = excl;
        excl += in_deg[i];
        int od = out_deg[i]; if (od < 1) od = 1;
        int id = in_deg[i];  if (id < 1) id = 1;
        src_norm[i] = rsqrtf((float)od);
        dst_norm[i] = rsqrtf((float)id);
    }
    if (t == 1023) off[N] = lsum[1023];
}

// ---------------------------------------------------------------------------
// csr fill: also materializes csr_norm[pos] = src_norm[src] so the aggregate
// reads norms SEQUENTIALLY (wave-uniform) instead of 3x random 4B gathers.
// ---------------------------------------------------------------------------
__global__ void csr_fill(const int* __restrict__ src, const int* __restrict__ dst,
                         int* __restrict__ cursor, int* __restrict__ csr_src,
                         float* __restrict__ csr_norm,
                         const float* __restrict__ src_norm) {
    int e = blockIdx.x * blockDim.x + threadIdx.x;
    if (e >= E) return;
    int s = src[e];
    int d = dst[e];
    int pos = atomicAdd(&cursor[d], 1);
    csr_src[pos] = s;
    csr_norm[pos] = src_norm[s];
}

// ---------------------------------------------------------------------------
// Fused BN + gather-aggregate. One wave per node, full 1KB rows.
// MLP-focused rewrite:
//   - readfirstlane edge range -> idx/norm loads are provably wave-uniform
//     (scalar SMEM loads: frees VMEM issue slots + address VGPRs)
//   - 8-edge unroll: 8 independent 1KB row loads in flight per wave
//   - single acc[8]; BN coefs computed AFTER the loop (loop-live VGPR <= 64
//     so occupancy stays 32 waves/CU: MLP/CU = 32x8 rows vs r1's 32x4)
// ---------------------------------------------------------------------------
__global__ __launch_bounds__(256) void aggregate_bn(
    const _Float16* __restrict__ x, const int* __restrict__ off,
    const int* __restrict__ csr_src, const float* __restrict__ csr_norm,
    const float* __restrict__ dst_norm, const float* __restrict__ stats,
    const float* __restrict__ gamma, const float* __restrict__ beta,
    _Float16* __restrict__ agg) {
    int wid = (blockIdx.x * 256 + threadIdx.x) >> 6;
    if (wid >= N) return;
    int lane = threadIdx.x & 63;
    int c0 = lane * 8;
    const _Float16* xp = x + c0;

    int e0 = __builtin_amdgcn_readfirstlane(off[wid]);
    int e1 = __builtin_amdgcn_readfirstlane(off[wid + 1]);

    float a[8] = {};
    float t = 0.f;
    int e = e0;
    for (; e + 8 <= e1; e += 8) {
        int s0 = csr_src[e + 0];
        int s1 = csr_src[e + 1];
        int s2 = csr_src[e + 2];
        int s3 = csr_src[e + 3];
        int s4 = csr_src[e + 4];
        int s5 = csr_src[e + 5];
        int s6 = csr_src[e + 6];
        int s7 = csr_src[e + 7];
        float n0 = csr_norm[e + 0];
        float n1 = csr_norm[e + 1];
        float n2 = csr_norm[e + 2];
        float n3 = csr_norm[e + 3];
        float n4 = csr_norm[e + 4];
        float n5 = csr_norm[e + 5];
        float n6 = csr_norm[e + 6];
        float n7 = csr_norm[e + 7];
        half8 v0 = *(const half8*)(xp + (size_t)s0 * D);
        half8 v1 = *(const half8*)(xp + (size_t)s1 * D);
        half8 v2 = *(const half8*)(xp + (size_t)s2 * D);
        half8 v3 = *(const half8*)(xp + (size_t)s3 * D);
        half8 v4 = *(const half8*)(xp + (size_t)s4 * D);
        half8 v5 = *(const half8*)(xp + (size_t)s5 * D);
        half8 v6 = *(const half8*)(xp + (size_t)s6 * D);
        half8 v7 = *(const half8*)(xp + (size_t)s7 * D);
        t += ((n0 + n1) + (n2 + n3)) + ((n4 + n5) + (n6 + n7));
#pragma unroll
        for (int k = 0; k < 8; ++k) {
            float p0 = (float)v0[k] * n0 + (float)v1[k] * n1;
            float p1 = (float)v2[k] * n2 + (float)v3[k] * n3;
            float p2 = (float)v4[k] * n4 + (float)v5[k] * n5;
            float p3 = (float)v6[k] * n6 + (float)v7[k] * n7;
            a[k] += (p0 + p1) + (p2 + p3);
        }
    }
    for (; e < e1; ++e) {
        int s0 = csr_src[e];
        float n0 = csr_norm[e];
        half8 v0 = *(const half8*)(xp + (size_t)s0 * D);
        t += n0;
#pragma unroll
        for (int k = 0; k < 8; ++k) a[k] += (float)v0[k] * n0;
    }

    // BN coefficients after the loop (not loop-live)
    float dn = dst_norm[wid];
    const float invN = 1.0f / (float)N;
    half8 o;
#pragma unroll
    for (int k = 0; k < 8; ++k) {
        int c = c0 + k;
        float mu = stats[c] * invN;
        float var = stats[D + c] * invN - mu * mu;
        float sc = gamma[c] * rsqrtf(var + EPS);
        float sh = beta[c] - mu * sc;
        o[k] = (_Float16)(dn * (sc * a[k] + sh * t));
    }
    *(half8*)(agg + (size_t)wid * D + c0) = o;
}

// ---------------------------------------------------------------------------
// C = relu(A @ W + bias) via f16 MFMA -- v3 (R8 verified, unchanged).
// 128x128 tile, 4 waves, BK=64 double-buffered, XOR chunk-swizzle.
// ---------------------------------------------------------------------------
template <typename OutT, bool STATS>
__global__ __launch_bounds__(256) void mm_f16_relu(
    const _Float16* __restrict__ A, const _Float16* __restrict__ Bt,
    const float* __restrict__ bias, OutT* __restrict__ C, int M,
    float* __restrict__ stats) {
    __shared__ __align__(16) _Float16 As[2][128 * 64];   // 16 KB each
    __shared__ __align__(16) _Float16 Bs[2][128 * 64];
    const int tid  = threadIdx.x;
    const int wave = tid >> 6;
    const int lane = tid & 63;
    const int quad = lane >> 4;
    const int l16  = lane & 15;
    const int row0 = blockIdx.x * 128;
    const int col0 = blockIdx.y * 128;
    const int wm = (wave & 1) * 64;
    const int wn = (wave >> 1) * 64;

    const int srl = lane >> 3;          // row-in-slab 0..7
    const int sq  = lane & 7;           // dest chunk 0..7
    const int sqs = (sq ^ srl) * 8;     // pre-swizzled source col (halves)

    const _Float16* gA[4];
    const _Float16* gB[4];
#pragma unroll
    for (int j = 0; j < 4; ++j) {
        int ar = row0 + wave * 32 + j * 8 + srl;
        if (ar >= M) ar = M - 1;
        gA[j] = A + (size_t)ar * D + sqs;
        int br = col0 + wave * 32 + j * 8 + srl;
        gB[j] = Bt + (size_t)br * D + sqs;
    }

    const int l7 = l16 & 7;
    const int swz0 = (quad ^ l7) * 8;
    const int swz1 = ((4 + quad) ^ l7) * 8;

    floatx4 acc[4][4] = {};

    auto stage = [&](int buf, int k0) {
        _Float16* as = As[buf] + (wave * 32) * 64;
        _Float16* bs = Bs[buf] + (wave * 32) * 64;
#pragma unroll
        for (int j = 0; j < 4; ++j) {
            glds16(gA[j] + k0, as + j * 8 * 64);
            glds16(gB[j] + k0, bs + j * 8 * 64);
        }
    };

    stage(0, 0);
    __syncthreads();

    int cur = 0;
    for (int kt = 0; kt < 8; ++kt) {
        if (kt < 7) stage(cur ^ 1, (kt + 1) * 64);
        const _Float16* asb = As[cur];
        const _Float16* bsb = Bs[cur];
        half8 af0[4], af1[4], bf0[4], bf1[4];
#pragma unroll
        for (int i = 0; i < 4; ++i) {
            int r = wm + i * 16 + l16;
            af0[i] = *(const half8*)(asb + r * 64 + swz0);
            af1[i] = *(const half8*)(asb + r * 64 + swz1);
        }
#pragma unroll
        for (int j = 0; j < 4; ++j) {
            int r = wn + j * 16 + l16;
            bf0[j] = *(const half8*)(bsb + r * 64 + swz0);
            bf1[j] = *(const half8*)(bsb + r * 64 + swz1);
        }
#pragma unroll
        for (int i = 0; i < 4; ++i)
#pragma unroll
            for (int j = 0; j < 4; ++j)
                acc[i][j] = __builtin_amdgcn_mfma_f32_16x16x32_f16(
                    af0[i], bf0[j], acc[i][j], 0, 0, 0);
#pragma unroll
        for (int i = 0; i < 4; ++i)
#pragma unroll
            for (int j = 0; j < 4; ++j)
                acc[i][j] = __builtin_amdgcn_mfma_f32_16x16x32_f16(
                    af1[i], bf1[j], acc[i][j], 0, 0, 0);
        __syncthreads();
        cur ^= 1;
    }

    float s[4] = {}, q[4] = {};
    for (int i = 0; i < 4; ++i) {
        for (int r = 0; r < 4; ++r) {
            int row = row0 + wm + i * 16 + quad * 4 + r;
            bool valid = row < M;
            for (int j = 0; j < 4; ++j) {
                int col = col0 + wn + j * 16 + l16;
                float v = acc[i][j][r] + bias[col];
                v = v > 0.f ? v : 0.f;
                if (valid) {
                    C[(size_t)row * D + col] = (OutT)v;
                    if (STATS) { s[j] += v; q[j] += v * v; }
                }
            }
        }
    }
    if (STATS) {
        for (int j = 0; j < 4; ++j) {
            float sv = s[j], qv = q[j];
            sv += __shfl_xor(sv, 16); sv += __shfl_xor(sv, 32);
            qv += __shfl_xor(qv, 16); qv += __shfl_xor(qv, 32);
            if (quad == 0) {
                int col = col0 + wn + j * 16 + l16;
                atomicAdd(&stats[col], sv);
                atomicAdd(&stats[D + col], qv);
            }
        }
    }
}

// ---------------------------------------------------------------------------
extern "C" void kernel_launch(void* const* d_in, const int* in_sizes, int n_in,
                              void* d_out, int out_size, void* d_ws, size_t ws_size,
                              hipStream_t stream) {
    const float* x_in  = (const float*)d_in[0];
    const int*   src   = (const int*)d_in[1];
    const int*   dst   = (const int*)d_in[2];
    const float* gamma = (const float*)d_in[3];
    const float* beta  = (const float*)d_in[4];
    const float* W     = (const float*)d_in[5];
    const float* b     = (const float*)d_in[6];
    float* out = (float*)d_out;

    // workspace carve-up (16B-aligned segments first)
    char* p = (char*)d_ws;
    _Float16* x16 = (_Float16*)p;  p += (size_t)N * D * 2;       // 10.24 MB
    _Float16* agg = (_Float16*)p;  p += (size_t)N * D * 2;       // 10.24 MB
    _Float16* Wt  = (_Float16*)p;  p += (size_t)L * D * D * 2;   // 1.57 MB
    float* src_norm = (float*)p;   p += (size_t)N * 4;
    float* dst_norm = (float*)p;   p += (size_t)N * 4;
    float* csr_norm = (float*)p;   p += (size_t)E * 4;           // 0.64 MB
    // contiguous zero-init region: out_deg, in_deg, stats0..2
    int* out_deg   = (int*)p;      p += (size_t)N * 4;
    int* in_deg    = (int*)p;      p += (size_t)N * 4;
    float* stats0  = (float*)p;    p += 2 * D * 4;
    float* stats1  = (float*)p;    p += 2 * D * 4;
    float* stats2  = (float*)p;    p += 2 * D * 4;
    int* csr_off   = (int*)p;      p += (size_t)(N + 1) * 4;
    int* cursor    = (int*)p;      p += (size_t)N * 4;
    int* csr_src   = (int*)p;      p += (size_t)E * 4;

    float* stats_in[3] = {stats0, stats1, stats2};

    // --- setup ---
    hipMemsetAsync(out_deg, 0, (2 * (size_t)N + 6 * D) * sizeof(int), stream);
    mega_setup<<<MEGA_BLOCKS, 256, 0, stream>>>(src, dst, x_in, W,
                                                out_deg, in_deg, x16, stats0, Wt);
    scan_indeg<<<1, 1024, 0, stream>>>(in_deg, out_deg, csr_off, cursor,
                                       src_norm, dst_norm);
    csr_fill<<<DEG_BLOCKS, 256, 0, stream>>>(src, dst, cursor, csr_src,
                                             csr_norm, src_norm);

    dim3 mm_grid((N + 127) / 128, D / 128);
    const int agg_blocks = (N + 3) / 4;  // 4 waves per 256-thread block

    for (int l = 0; l < L; ++l) {
        const float* gl  = gamma + (size_t)l * D;
        const float* bl  = beta + (size_t)l * D;
        const _Float16* Wl = Wt + (size_t)l * D * D;
        const float* bil = b + (size_t)l * D;

        aggregate_bn<<<agg_blocks, 256, 0, stream>>>(
            x16, csr_off, csr_src, csr_norm, dst_norm, stats_in[l], gl, bl, agg);
        if (l == L - 1) {
            mm_f16_relu<float, false><<<mm_grid, 256, 0, stream>>>(
                agg, Wl, bil, out, N, nullptr);
        } else {
            mm_f16_relu<_Float16, true><<<mm_grid, 256, 0, stream>>>(
                agg, Wl, bil, x16, N, stats_in[l + 1]);
        }
    }
}